// Round 1
// baseline (352.627 us; speedup 1.0000x reference)
//
#include <hip/hip_runtime.h>

// ---------------------------------------------------------------------------
// PhysNet stack, MI355X.
//   proto[i] = h_self[i] + fmtab[i] * (S[i] @ W_gate),  S module-invariant.
// ONE fused chain kernel (80 GEMM stages). v2: 16-row / 512-thread blocks
// (8 waves), LDS 76.6 KB -> 2 blocks/CU = two independent barrier domains
// per CU (overlaps barrier/DMA drain of one block with compute of the
// other). Biases read directly from L2 (no sBias staging). Gather rewritten
// to 4-rows-per-load (dwordx4 per 16-lane group) with 8 loads in flight.
// ---------------------------------------------------------------------------

#define LN2F 0.69314718055994530942f
#define NB 128   // sort blocks

using short8  = __attribute__((ext_vector_type(8))) short;
using float4v = __attribute__((ext_vector_type(4))) float;
typedef const __attribute__((address_space(1))) unsigned int* gas1_t;
typedef __attribute__((address_space(3))) unsigned int* las3_t;

__device__ __forceinline__ float sspf(float x) {
  float ax = fabsf(x);
  return fmaxf(x, 0.0f) + __logf(1.0f + __expf(-ax)) - LN2F;
}

__device__ __forceinline__ unsigned short f2bf(float x) {
  return (unsigned short)((__float_as_uint(x) + 0x8000u) >> 16);  // RTN, <=0.5ulp
}

__device__ __forceinline__ unsigned short f2bf_ne(float x) {  // RTNE for weight prep
  unsigned int u = __float_as_uint(x);
  u += 0x7fffu + ((u >> 16) & 1u);
  return (unsigned short)(u >> 16);
}

__device__ __forceinline__ void dma16(const void* g, void* l) {
  __builtin_amdgcn_global_load_lds((gas1_t)(unsigned long long)g,
                                   (las3_t)(unsigned long long)l, 16, 0, 0);
}

// 8-wave block DMA: 32KB -> 4KB/wave, 16KB -> 2KB/wave
__device__ __forceinline__ void dma32k8(const unsigned short* g, unsigned short* l,
                                        int w, int lane) {
  const char* gb = (const char*)g + w * 4096 + lane * 16;
  char* lb = (char*)l + w * 4096;
  dma16(gb, lb);
  dma16(gb + 1024, lb + 1024);
  dma16(gb + 2048, lb + 2048);
  dma16(gb + 3072, lb + 3072);
}
__device__ __forceinline__ void dma16k8(const unsigned short* g, unsigned short* l,
                                        int w, int lane) {
  const char* gb = (const char*)g + w * 2048 + lane * 16;
  char* lb = (char*)l + w * 2048;
  dma16(gb, lb);
  dma16(gb + 1024, lb + 1024);
}

// ---------------------------------------------------------------------------
// S-path: LDS-hist radix sort (no global atomics) + gather
// ---------------------------------------------------------------------------
__global__ __launch_bounds__(256) void hist_pass(const int* __restrict__ idx,
                                                 unsigned int* __restrict__ H,
                                                 int n2p, int C) {
  __shared__ unsigned int h[8192];
  int b = blockIdx.x, tid = threadIdx.x;
  for (int i = tid; i < 8192; i += 256) h[i] = 0;
  __syncthreads();
  int s = b * C, e = min(s + C, n2p);
  for (int i = s + tid; i < e; i += 256) atomicAdd(&h[idx[i]], 1u);
  __syncthreads();
  for (int i = tid; i < 8192; i += 256) H[(size_t)b * 8192 + i] = h[i];
}

__global__ __launch_bounds__(256) void col_scan(unsigned int* __restrict__ H,
                                                unsigned int* __restrict__ tot) {
  int a = blockIdx.x * 256 + threadIdx.x;
  unsigned int run = 0;
  for (int b = 0; b < NB; ++b) {
    unsigned int v = H[(size_t)b * 8192 + a];
    H[(size_t)b * 8192 + a] = run;
    run += v;
  }
  tot[a] = run;
}

__global__ __launch_bounds__(256) void scan_kernel(const unsigned int* __restrict__ cnt,
                                                   unsigned int* __restrict__ off, int NA) {
  int t = threadIdx.x;
  unsigned int local[32], s = 0;
#pragma unroll
  for (int i = 0; i < 32; ++i) { local[i] = cnt[t * 32 + i]; s += local[i]; }
  unsigned int v = s;
  int lane = t & 63, w = t >> 6;
#pragma unroll
  for (int o = 1; o < 64; o <<= 1) {
    unsigned int u = __shfl_up(v, o, 64);
    if (lane >= o) v += u;
  }
  __shared__ unsigned int wt4[4];
  if (lane == 63) wt4[w] = v;
  __syncthreads();
  unsigned int base = 0;
  for (int k = 0; k < w; ++k) base += wt4[k];
  unsigned int excl = base + v - s;
#pragma unroll
  for (int i = 0; i < 32; ++i) { off[t * 32 + i] = excl; excl += local[i]; }
  if (t == 255) off[NA] = excl;
}

__global__ __launch_bounds__(256) void place_pass(const int* __restrict__ idx,
                                                  const unsigned int* __restrict__ H,
                                                  const unsigned int* __restrict__ off,
                                                  unsigned int* __restrict__ pairid,
                                                  int P, int C) {
  __shared__ unsigned int pos[8192];
  int b = blockIdx.x, tid = threadIdx.x;
  for (int i = tid; i < 8192; i += 256)
    pos[i] = off[i] + H[(size_t)b * 8192 + i];
  __syncthreads();
  int n2p = 2 * P;
  int s = b * C, e = min(s + C, n2p);
  for (int i = s + tid; i < e; i += 256) {
    int a = idx[i];
    unsigned int p = atomicAdd(&pos[a], 1u);
    pairid[p] = (i >= P) ? (unsigned int)(i - P) : (unsigned int)i;
  }
}

// Gather v2: each 16-lane group reads a full 256B radial row via dwordx4
// (4 rows per wave per load instruction), 8 loads in flight -> 32 entries
// per wave-iteration. Fully predicated via index clamp (always valid addr).
__global__ __launch_bounds__(256) void gather_kernel(const float* __restrict__ radial,
                                                     const unsigned int* __restrict__ off,
                                                     const unsigned int* __restrict__ pairid,
                                                     float* __restrict__ S) {
  __shared__ float4v red[3][16];
  int a = blockIdx.x;
  int lane = threadIdx.x & 63, w = threadIdx.x >> 6;
  int grp = lane >> 4, l16v = lane & 15;
  unsigned int b = off[a], e = off[a + 1];
  float4v acc = {0.f, 0.f, 0.f, 0.f};
  // entry j = base + k*16 + w*4 + grp : block-iter covers 128 entries
  for (unsigned int base = b; base < e; base += 128) {
    unsigned int pp[8];
#pragma unroll
    for (int k = 0; k < 8; ++k) {
      unsigned int j = base + k * 16 + w * 4 + grp;
      pp[k] = pairid[j < e ? j : b];          // clamped: always valid
    }
    float4v vv[8];
#pragma unroll
    for (int k = 0; k < 8; ++k)
      vv[k] = *(const float4v*)(radial + (size_t)pp[k] * 64 + l16v * 4);
#pragma unroll
    for (int k = 0; k < 8; ++k) {
      unsigned int j = base + k * 16 + w * 4 + grp;
      if (j < e) acc += vv[k];
    }
  }
  // reduce across the 4 row-groups in-wave
#pragma unroll
  for (int o = 16; o < 64; o <<= 1) {
#pragma unroll
    for (int cc = 0; cc < 4; ++cc) acc[cc] += __shfl_xor(acc[cc], o, 64);
  }
  if (w > 0 && grp == 0) red[w - 1][l16v] = acc;
  __syncthreads();
  if (w == 0 && grp == 0) {
    acc += red[0][l16v];
    acc += red[1][l16v];
    acc += red[2][l16v];
    *(float4v*)(S + (size_t)a * 64 + l16v * 4) = acc;
  }
}

// ---------------------------------------------------------------------------
// Weight prep: fp32 W[k][n] -> bf16, transposed + XOR-swizzled 16B chunks.
// chunk(n,j) at pos = n*16 + (j^(n&15))  (gate: n*8 + (j^(n&7)))
// ---------------------------------------------------------------------------
struct PrepArgs {
  const float* src[80];
  int isgate[80];
};

__global__ __launch_bounds__(256) void prep_weights(PrepArgs A, unsigned short* __restrict__ Wt) {
  int m = blockIdx.x;
  const float* s = A.src[m];
  unsigned short* d = Wt + (size_t)m * 16384;
  if (!A.isgate[m]) {
    for (int it = 0; it < 8; ++it) {
      int q = threadIdx.x + it * 256;
      int n = q & 127, j = q >> 7;
      unsigned short tmp[8];
#pragma unroll
      for (int cc = 0; cc < 8; ++cc) tmp[cc] = f2bf_ne(s[(8 * j + cc) * 128 + n]);
      *(uint4*)(d + (n * 16 + (j ^ (n & 15))) * 8) = *(uint4*)tmp;
    }
  } else {
    for (int it = 0; it < 4; ++it) {
      int q = threadIdx.x + it * 256;
      int n = q & 127, j = q >> 7;
      unsigned short tmp[8];
#pragma unroll
      for (int cc = 0; cc < 8; ++cc) tmp[cc] = f2bf_ne(s[(8 * j + cc) * 128 + n]);
      *(uint4*)(d + (n * 8 + (j ^ (n & 7))) * 8) = *(uint4*)tmp;
    }
  }
}

struct BiasArgs {
  const float* p[17];
  int stride[17];
  const float* b_out;
};

__global__ __launch_bounds__(256) void pack_bias(BiasArgs B, float* __restrict__ dst) {
  int l = blockIdx.x;
  for (int i = threadIdx.x; i < 17 * 128; i += 256) {
    int s = i >> 7;
    dst[(size_t)l * 2304 + i] = B.p[s][l * B.stride[s] + (i & 127)];
  }
  if (threadIdx.x == 0) dst[(size_t)l * 2304 + 17 * 128] = B.b_out[l];
}

// ---------------------------------------------------------------------------
// Fused chain kernel v2: 512 threads = 8 waves; wave c owns cols 16c..16c+15
// of this block's 16 rows. 512 blocks -> 2 blocks/CU (LDS 76.6 KB), two
// independent barrier domains per CU.
// ---------------------------------------------------------------------------
struct ChainArgs {
  const float* feat_in;
  const float* S;
  const unsigned short* wt;      // 80 slots x 16384 shorts
  const float* bias_pack;        // 5 x 2304 floats
  float* feat_out;
  float* energy;
};

__device__ __forceinline__ void gemm128s(const unsigned short* sA_, const unsigned short* sW,
                                         int col0, int l16, int quad, float4v* acc) {
  const unsigned short* ar = sA_ + l16 * 136 + quad * 8;
  short8 a0 = *(const short8*)(ar);
  short8 a1 = *(const short8*)(ar + 32);
  short8 a2 = *(const short8*)(ar + 64);
  short8 a3 = *(const short8*)(ar + 96);
  const unsigned short* bb = sW + col0 * 128;
  *acc = __builtin_amdgcn_mfma_f32_16x16x32_bf16(a0, *(const short8*)(bb + ((quad + 0) ^ l16) * 8), *acc, 0, 0, 0);
  *acc = __builtin_amdgcn_mfma_f32_16x16x32_bf16(a1, *(const short8*)(bb + ((quad + 4) ^ l16) * 8), *acc, 0, 0, 0);
  *acc = __builtin_amdgcn_mfma_f32_16x16x32_bf16(a2, *(const short8*)(bb + ((quad + 8) ^ l16) * 8), *acc, 0, 0, 0);
  *acc = __builtin_amdgcn_mfma_f32_16x16x32_bf16(a3, *(const short8*)(bb + ((quad + 12) ^ l16) * 8), *acc, 0, 0, 0);
}

__device__ __forceinline__ void gemm64s(const unsigned short* sS_, const unsigned short* sW,
                                        int col0, int l16, int quad, float4v* acc) {
  const unsigned short* ar = sS_ + l16 * 72 + quad * 8;
  short8 a0 = *(const short8*)(ar);
  short8 a1 = *(const short8*)(ar + 32);
  int l8 = l16 & 7;
  const unsigned short* bb = sW + col0 * 64;
  *acc = __builtin_amdgcn_mfma_f32_16x16x32_bf16(a0, *(const short8*)(bb + ((quad + 0) ^ l8) * 8), *acc, 0, 0, 0);
  *acc = __builtin_amdgcn_mfma_f32_16x16x32_bf16(a1, *(const short8*)(bb + ((quad + 4) ^ l8) * 8), *acc, 0, 0, 0);
}

__device__ __forceinline__ void write_ssp_A(unsigned short* sA_, const float4v v,
                                            int col0, int quad) {
#pragma unroll
  for (int r = 0; r < 4; ++r)
    sA_[(quad * 4 + r) * 136 + col0] = f2bf(sspf(v[r]));
}

__global__ __launch_bounds__(512, 4) void chain_kernel(ChainArgs A) {
  __shared__ __align__(16) unsigned short swb[2][16384];   // 64 KB weight dbuf
  __shared__ __align__(16) unsigned short sA[2][16 * 136]; // 8.5 KB
  __shared__ __align__(16) unsigned short sS[16 * 72];     // 2.25 KB
  __shared__ float sE[16];

  const int tid  = threadIdx.x;
  const int row0 = blockIdx.x * 16;
  const int lane = tid & 63;
  const int w    = tid >> 6;       // 0..7 = col 16-chunk
  const int l16  = lane & 15;
  const int quad = lane >> 4;
  const int col0 = 16 * w + l16;
  const float* bcol = A.bias_pack + col0;   // per-stage bias column base

  dma16k8(A.wt, swb[0], w, lane);   // module-0 gate

  for (int i = tid; i < 16 * 64; i += 512) {
    int r = i >> 6, k = i & 63;
    sS[r * 72 + k] = f2bf(A.S[(size_t)(row0 + r) * 64 + k]);
  }
  for (int i = tid; i < 16 * 128; i += 512) {
    int r = i >> 7, k = i & 127;
    sA[0][r * 136 + k] = f2bf(sspf(A.feat_in[(size_t)(row0 + r) * 128 + k]));
  }
  float4v ff;
#pragma unroll
  for (int r = 0; r < 4; ++r)
    ff[r] = A.feat_in[(size_t)(row0 + quad * 4 + r) * 128 + col0];
  if (tid < 16) sE[tid] = 0.0f;
  __syncthreads();

  const float4v Z = {0.f, 0.f, 0.f, 0.f};
  float4v gG, fm, xf, t4;
  float p0 = 0.f, p1 = 0.f, p2 = 0.f, p3 = 0.f, bsum = 0.f;

#pragma unroll 1
  for (int l = 0; l < 5; ++l) {
    const size_t slot0 = (size_t)l * 16 * 16384;
    const float* bl = bcol + l * 2304;

    // ---- t=0: gate GEMM; DMA W_J
    dma32k8(A.wt + slot0 + 16384, swb[1], w, lane);
    gG = Z;
    gemm64s(sS, swb[0], col0, l16, quad, &gG);
    __syncthreads();

    // ---- t=1: W_J -> fm
    {
      float bv = bl[0 * 128];
      dma32k8(A.wt + slot0 + 2 * 16384, swb[0], w, lane);
      fm = Z;
      gemm128s(sA[0], swb[1], col0, l16, quad, &fm);
#pragma unroll
      for (int r = 0; r < 4; ++r) fm[r] = sspf(fm[r] + bv);
    }
    __syncthreads();

    // ---- t=2: W_I; proto = fm*gG + ssp(t4+b) -> sA1
    {
      float bv = bl[1 * 128];
      dma32k8(A.wt + slot0 + 3 * 16384, swb[1], w, lane);
      t4 = Z;
      gemm128s(sA[0], swb[0], col0, l16, quad, &t4);
#pragma unroll
      for (int r = 0; r < 4; ++r) xf[r] = fm[r] * gG[r] + sspf(t4[r] + bv);
    }
    write_ssp_A(sA[1], xf, col0, quad);
    __syncthreads();

    // ---- t=3..8: ri chain x3
#pragma unroll
    for (int jj = 0; jj < 3; ++jj) {
      const int th = 3 + 2 * jj;
      {
        float bv = bl[(th - 1) * 128];
        dma32k8(A.wt + slot0 + (size_t)(th + 1) * 16384, swb[th & 1 ? 0 : 1], w, lane);
        t4 = Z;
        gemm128s(sA[1], swb[th & 1], col0, l16, quad, &t4);
#pragma unroll
        for (int r = 0; r < 4; ++r) t4[r] += bv;
      }
      write_ssp_A(sA[0], t4, col0, quad);
      __syncthreads();

      const int tx = th + 1;
      {
        float bv = bl[(tx - 1) * 128];
        dma32k8(A.wt + slot0 + (size_t)(tx + 1) * 16384, swb[tx & 1 ? 0 : 1], w, lane);
        t4 = Z;
        gemm128s(sA[0], swb[tx & 1], col0, l16, quad, &t4);
#pragma unroll
        for (int r = 0; r < 4; ++r) xf[r] += t4[r] + bv;
      }
      write_ssp_A(sA[1], xf, col0, quad);
      __syncthreads();
    }

    // ---- t=9: W_int: xf = ff*gvec + t4 + b  (read sA1/swb1, write sA0)
    {
      float bv = bl[8 * 128];
      float gv = bl[15 * 128];
      dma32k8(A.wt + slot0 + 10 * 16384, swb[0], w, lane);
      t4 = Z;
      gemm128s(sA[1], swb[1], col0, l16, quad, &t4);
#pragma unroll
      for (int r = 0; r < 4; ++r) xf[r] = ff[r] * gv + t4[r] + bv;
    }
    write_ssp_A(sA[0], xf, col0, quad);
    __syncthreads();

    // ---- t=10..13: ra chain x2
#pragma unroll
    for (int jj = 0; jj < 2; ++jj) {
      const int th = 10 + 2 * jj;
      {
        float bv = bl[(th - 1) * 128];
        dma32k8(A.wt + slot0 + (size_t)(th + 1) * 16384, swb[th & 1 ? 0 : 1], w, lane);
        t4 = Z;
        gemm128s(sA[0], swb[th & 1], col0, l16, quad, &t4);
#pragma unroll
        for (int r = 0; r < 4; ++r) t4[r] += bv;
      }
      write_ssp_A(sA[1], t4, col0, quad);
      __syncthreads();

      const int tx = th + 1;
      {
        float bv = bl[(tx - 1) * 128];
        dma32k8(A.wt + slot0 + (size_t)(tx + 1) * 16384, swb[tx & 1 ? 0 : 1], w, lane);
        t4 = Z;
        gemm128s(sA[1], swb[tx & 1], col0, l16, quad, &t4);
#pragma unroll
        for (int r = 0; r < 4; ++r) xf[r] += t4[r] + bv;
      }
      write_ssp_A(sA[0], xf, col0, quad);
      __syncthreads();
    }

    // xf is feat2
    ff = xf;
    if (l == 4) {
#pragma unroll
      for (int r = 0; r < 4; ++r)
        A.feat_out[(size_t)(row0 + quad * 4 + r) * 128 + col0] = xf[r];
    }

    // ---- t=14: ro_W1 (read sA0/swb0, write sA1)
    {
      float bv = bl[13 * 128];
      dma32k8(A.wt + slot0 + 15 * 16384, swb[1], w, lane);
      t4 = Z;
      gemm128s(sA[0], swb[0], col0, l16, quad, &t4);
#pragma unroll
      for (int r = 0; r < 4; ++r) t4[r] += bv;
    }
    write_ssp_A(sA[1], t4, col0, quad);
    __syncthreads();

    // ---- t=15: ro_W2; energy; DMA next gate -> swb0
    {
      float bv = bl[14 * 128];
      float wv = bl[16 * 128];
      if (l < 4) dma16k8(A.wt + slot0 + 16 * 16384, swb[0], w, lane);
      t4 = Z;
      gemm128s(sA[1], swb[1], col0, l16, quad, &t4);
      p0 += sspf(xf[0] + t4[0] + bv) * wv;
      p1 += sspf(xf[1] + t4[1] + bv) * wv;
      p2 += sspf(xf[2] + t4[2] + bv) * wv;
      p3 += sspf(xf[3] + t4[3] + bv) * wv;
    }
    bsum += A.bias_pack[l * 2304 + 17 * 128];
    __syncthreads();
  }

  // ---- energy reduction (within 16-lane groups, then across 8 c-waves)
#pragma unroll
  for (int o = 1; o < 16; o <<= 1) {
    p0 += __shfl_xor(p0, o, 64);
    p1 += __shfl_xor(p1, o, 64);
    p2 += __shfl_xor(p2, o, 64);
    p3 += __shfl_xor(p3, o, 64);
  }
  if (l16 == 0) {
    atomicAdd(&sE[quad * 4 + 0], p0);
    atomicAdd(&sE[quad * 4 + 1], p1);
    atomicAdd(&sE[quad * 4 + 2], p2);
    atomicAdd(&sE[quad * 4 + 3], p3);
  }
  __syncthreads();
  if (tid < 16) A.energy[row0 + tid] = sE[tid] + bsum;
}

// ---------------------------------------------------------------------------
extern "C" void kernel_launch(void* const* d_in, const int* in_sizes, int n_in,
                              void* d_out, int out_size, void* d_ws, size_t ws_size,
                              hipStream_t stream) {
  const float* features = (const float*)d_in[1];
  const float* radial   = (const float*)d_in[2];
  const int*   idx12    = (const int*)  d_in[3];
  const float* W_I    = (const float*)d_in[4];
  const float* b_I    = (const float*)d_in[5];
  const float* W_J    = (const float*)d_in[6];
  const float* b_J    = (const float*)d_in[7];
  const float* W_gate = (const float*)d_in[8];
  const float* gvec   = (const float*)d_in[9];
  const float* W_int  = (const float*)d_in[10];
  const float* b_int  = (const float*)d_in[11];
  const float* ri_W1  = (const float*)d_in[12];
  const float* ri_b1  = (const float*)d_in[13];
  const float* ri_W2  = (const float*)d_in[14];
  const float* ri_b2  = (const float*)d_in[15];
  const float* ra_W1  = (const float*)d_in[16];
  const float* ra_b1  = (const float*)d_in[17];
  const float* ra_W2  = (const float*)d_in[18];
  const float* ra_b2  = (const float*)d_in[19];
  const float* ro_W1  = (const float*)d_in[20];
  const float* ro_b1  = (const float*)d_in[21];
  const float* ro_W2  = (const float*)d_in[22];
  const float* ro_b2  = (const float*)d_in[23];
  const float* W_out  = (const float*)d_in[24];
  const float* b_out  = (const float*)d_in[25];

  const int N = in_sizes[1] / 128;   // 8192
  const int P = in_sizes[3] / 2;     // 400000
  const int L = in_sizes[25];        // 5
  const int n2p = 2 * P;
  const int C = (n2p + NB - 1) / NB;

  // ws layout: S | bias_pack | Wt | H | tot | off | pairid
  float* S = (float*)d_ws;
  float* bias_pack = S + (size_t)N * 64;
  unsigned short* Wt = (unsigned short*)(bias_pack + 5 * 2304);
  unsigned int* H      = (unsigned int*)(Wt + (size_t)80 * 16384);
  unsigned int* tot    = H + (size_t)NB * 8192;
  unsigned int* off    = tot + N;
  unsigned int* pairid = off + N + 4;

  // ---- weight prep (consumption order: gate,WJ,WI,ri*6,Wint,ra*4,ro*2)
  PrepArgs pa;
  for (int l = 0; l < L; ++l) {
    const float* fx[16] = {
      W_gate + l * 8192,
      W_J + l * 16384, W_I + l * 16384,
      ri_W1 + (l * 3 + 0) * 16384, ri_W2 + (l * 3 + 0) * 16384,
      ri_W1 + (l * 3 + 1) * 16384, ri_W2 + (l * 3 + 1) * 16384,
      ri_W1 + (l * 3 + 2) * 16384, ri_W2 + (l * 3 + 2) * 16384,
      W_int + l * 16384,
      ra_W1 + (l * 2 + 0) * 16384, ra_W2 + (l * 2 + 0) * 16384,
      ra_W1 + (l * 2 + 1) * 16384, ra_W2 + (l * 2 + 1) * 16384,
      ro_W1 + l * 16384, ro_W2 + l * 16384 };
    for (int t = 0; t < 16; ++t) { pa.src[l * 16 + t] = fx[t]; pa.isgate[l * 16 + t] = (t == 0); }
  }
  prep_weights<<<80, 256, 0, stream>>>(pa, Wt);

  BiasArgs ba;
  const float* bp[17] = { b_J, b_I,
    ri_b1, ri_b2, ri_b1 + 128, ri_b2 + 128, ri_b1 + 256, ri_b2 + 256,
    b_int, ra_b1, ra_b2, ra_b1 + 128, ra_b2 + 128, ro_b1, ro_b2, gvec, W_out };
  int st[17] = {128,128, 384,384,384,384,384,384, 128, 256,256,256,256, 128,128,128,128};
  for (int q = 0; q < 17; ++q) { ba.p[q] = bp[q]; ba.stride[q] = st[q]; }
  ba.b_out = b_out;
  pack_bias<<<5, 256, 0, stream>>>(ba, bias_pack);

  // ---- S via LDS-hist sort + gather (no global atomics)
  hist_pass<<<NB, 256, 0, stream>>>(idx12, H, n2p, C);
  col_scan<<<32, 256, 0, stream>>>(H, tot);
  scan_kernel<<<1, 256, 0, stream>>>(tot, off, N);
  place_pass<<<NB, 256, 0, stream>>>(idx12, H, off, pairid, P, C);
  gather_kernel<<<N, 256, 0, stream>>>(radial, off, pairid, S);

  // ---- fused 5-module chain: 512 blocks x 512 threads, 2 blocks/CU
  ChainArgs ca;
  ca.feat_in   = features;
  ca.S         = S;
  ca.wt        = Wt;
  ca.bias_pack = bias_pack;
  ca.energy    = (float*)d_out;
  ca.feat_out  = (float*)d_out + N;
  chain_kernel<<<N / 16, 512, 0, stream>>>(ca);
}

// Round 2
// 328.849 us; speedup vs baseline: 1.0723x; 1.0723x over previous
//
#include <hip/hip_runtime.h>

// ---------------------------------------------------------------------------
// PhysNet stack, MI355X.  v3:
//  - chain back to 32-row/16-wave/256-block (v2's 2-block split regressed:
//    doubled per-CU weight DMA, no anti-phase gain).
//  - gate GEMM merged into stage 1 via dedicated sG buffer: 15 barriers/module.
//  - all LDS addresses hoisted, module body macro'd on swb parity (compile-time
//    offsets; no per-stage address recompute after barriers).
//  - biases back in LDS (double-buffered, DMA-staged one module ahead): no
//    per-stage vmem loads besides weight DMA (no mid-stage vmcnt drains).
//  - launch fusion: prep+bias+hist in one kernel; scan folded into place.
// ---------------------------------------------------------------------------

#define LN2F 0.69314718055994530942f
#define NB 128   // sort blocks

using short8  = __attribute__((ext_vector_type(8))) short;
using float4v = __attribute__((ext_vector_type(4))) float;
typedef const __attribute__((address_space(1))) unsigned int* gas1_t;
typedef __attribute__((address_space(3))) unsigned int* las3_t;

__device__ __forceinline__ float sspf(float x) {
  float ax = fabsf(x);
  return fmaxf(x, 0.0f) + __logf(1.0f + __expf(-ax)) - LN2F;
}

__device__ __forceinline__ unsigned short f2bf(float x) {
  return (unsigned short)((__float_as_uint(x) + 0x8000u) >> 16);  // RTN, <=0.5ulp
}

__device__ __forceinline__ unsigned short f2bf_ne(float x) {  // RTNE for weight prep
  unsigned int u = __float_as_uint(x);
  u += 0x7fffu + ((u >> 16) & 1u);
  return (unsigned short)(u >> 16);
}

__device__ __forceinline__ void dma16(const void* g, void* l) {
  __builtin_amdgcn_global_load_lds((gas1_t)(unsigned long long)g,
                                   (las3_t)(unsigned long long)l, 16, 0, 0);
}

// 16-wave block DMA: 32KB -> 2KB/wave, 16KB -> 1KB/wave
__device__ __forceinline__ void dma32k(const unsigned short* g, unsigned short* l,
                                       int w, int lane) {
  const char* gb = (const char*)g + w * 2048 + lane * 16;
  char* lb = (char*)l + w * 2048;
  dma16(gb, lb);
  dma16(gb + 1024, lb + 1024);
}
__device__ __forceinline__ void dma16k(const unsigned short* g, unsigned short* l,
                                       int w, int lane) {
  dma16((const char*)g + w * 1024 + lane * 16, (char*)l + w * 1024);
}

// ---------------------------------------------------------------------------
// K1: fused prep_weights (blocks 0..79) + pack_bias (80..84) + hist (85..212)
// ---------------------------------------------------------------------------
struct K1Args {
  const float* wsrc[80];
  int isgate[80];
  const float* bp[17];
  int bstride[17];
  const float* b_out;
  const int* idx;
  unsigned short* Wt;
  float* bias_pack;
  unsigned int* H;
  int n2p, C;
};

__global__ __launch_bounds__(256) void k1_prep(K1Args K) {
  __shared__ unsigned int h[8192];
  int b = blockIdx.x, tid = threadIdx.x;
  if (b < 80) {
    const float* s = K.wsrc[b];
    unsigned short* d = K.Wt + (size_t)b * 16384;
    if (!K.isgate[b]) {
      for (int it = 0; it < 8; ++it) {
        int q = tid + it * 256;
        int n = q & 127, j = q >> 7;
        unsigned short tmp[8];
#pragma unroll
        for (int cc = 0; cc < 8; ++cc) tmp[cc] = f2bf_ne(s[(8 * j + cc) * 128 + n]);
        *(uint4*)(d + (n * 16 + (j ^ (n & 15))) * 8) = *(uint4*)tmp;
      }
    } else {
      for (int it = 0; it < 4; ++it) {
        int q = tid + it * 256;
        int n = q & 127, j = q >> 7;
        unsigned short tmp[8];
#pragma unroll
        for (int cc = 0; cc < 8; ++cc) tmp[cc] = f2bf_ne(s[(8 * j + cc) * 128 + n]);
        *(uint4*)(d + (n * 8 + (j ^ (n & 7))) * 8) = *(uint4*)tmp;
      }
    }
  } else if (b < 85) {
    int l = b - 80;
    for (int i = tid; i < 17 * 128; i += 256) {
      int s = i >> 7;
      K.bias_pack[(size_t)l * 2304 + i] = K.bp[s][l * K.bstride[s] + (i & 127)];
    }
    if (tid == 0) K.bias_pack[(size_t)l * 2304 + 17 * 128] = K.b_out[l];
  } else {
    int blk = b - 85;
    for (int i = tid; i < 8192; i += 256) h[i] = 0;
    __syncthreads();
    int s = blk * K.C, e = min(s + K.C, K.n2p);
    for (int i = s + tid; i < e; i += 256) atomicAdd(&h[K.idx[i]], 1u);
    __syncthreads();
    for (int i = tid; i < 8192; i += 256) K.H[(size_t)blk * 8192 + i] = h[i];
  }
}

__global__ __launch_bounds__(256) void col_scan(unsigned int* __restrict__ H,
                                                unsigned int* __restrict__ tot) {
  int a = blockIdx.x * 256 + threadIdx.x;
  unsigned int run = 0;
  for (int b = 0; b < NB; ++b) {
    unsigned int v = H[(size_t)b * 8192 + a];
    H[(size_t)b * 8192 + a] = run;
    run += v;
  }
  tot[a] = run;
}

// place with inline scan of tot (each block redundantly; block 0 publishes off)
__global__ __launch_bounds__(256) void place_pass(const int* __restrict__ idx,
                                                  const unsigned int* __restrict__ H,
                                                  const unsigned int* __restrict__ tot,
                                                  unsigned int* __restrict__ off_out,
                                                  unsigned int* __restrict__ pairid,
                                                  int P, int C) {
  __shared__ unsigned int pos[8192];
  __shared__ unsigned int wt4[4];
  int b = blockIdx.x, tid = threadIdx.x;
  unsigned int local[32], s = 0;
#pragma unroll
  for (int i = 0; i < 32; ++i) { local[i] = tot[tid * 32 + i]; s += local[i]; }
  unsigned int v = s;
  int lane = tid & 63, wv = tid >> 6;
#pragma unroll
  for (int o = 1; o < 64; o <<= 1) {
    unsigned int u = __shfl_up(v, o, 64);
    if (lane >= o) v += u;
  }
  if (lane == 63) wt4[wv] = v;
  __syncthreads();
  unsigned int base = 0;
  for (int k = 0; k < wv; ++k) base += wt4[k];
  unsigned int excl = base + v - s;
#pragma unroll
  for (int i = 0; i < 32; ++i) {
    pos[tid * 32 + i] = excl;
    if (b == 0) off_out[tid * 32 + i] = excl;
    excl += local[i];
  }
  if (b == 0 && tid == 255) off_out[8192] = excl;
  __syncthreads();
  for (int i = tid; i < 8192; i += 256) pos[i] += H[(size_t)b * 8192 + i];
  __syncthreads();
  int n2p = 2 * P;
  int s2 = b * C, e2 = min(s2 + C, n2p);
  for (int i = s2 + tid; i < e2; i += 256) {
    int a = idx[i];
    unsigned int p = atomicAdd(&pos[a], 1u);
    pairid[p] = (i >= P) ? (unsigned int)(i - P) : (unsigned int)i;
  }
}

// Gather: 16-lane group reads a full 256B radial row via dwordx4
__global__ __launch_bounds__(256) void gather_kernel(const float* __restrict__ radial,
                                                     const unsigned int* __restrict__ off,
                                                     const unsigned int* __restrict__ pairid,
                                                     float* __restrict__ S) {
  __shared__ float4v red[3][16];
  int a = blockIdx.x;
  int lane = threadIdx.x & 63, w = threadIdx.x >> 6;
  int grp = lane >> 4, l16v = lane & 15;
  unsigned int b = off[a], e = off[a + 1];
  float4v acc = {0.f, 0.f, 0.f, 0.f};
  for (unsigned int base = b; base < e; base += 128) {
    unsigned int pp[8];
#pragma unroll
    for (int k = 0; k < 8; ++k) {
      unsigned int j = base + k * 16 + w * 4 + grp;
      pp[k] = pairid[j < e ? j : b];          // clamped: always valid
    }
    float4v vv[8];
#pragma unroll
    for (int k = 0; k < 8; ++k)
      vv[k] = *(const float4v*)(radial + (size_t)pp[k] * 64 + l16v * 4);
#pragma unroll
    for (int k = 0; k < 8; ++k) {
      unsigned int j = base + k * 16 + w * 4 + grp;
      if (j < e) acc += vv[k];
    }
  }
#pragma unroll
  for (int o = 16; o < 64; o <<= 1) {
#pragma unroll
    for (int cc = 0; cc < 4; ++cc) acc[cc] += __shfl_xor(acc[cc], o, 64);
  }
  if (w > 0 && grp == 0) red[w - 1][l16v] = acc;
  __syncthreads();
  if (w == 0 && grp == 0) {
    acc += red[0][l16v];
    acc += red[1][l16v];
    acc += red[2][l16v];
    *(float4v*)(S + (size_t)a * 64 + l16v * 4) = acc;
  }
}

// ---------------------------------------------------------------------------
// Chain v3: 256 blocks x 1024 threads (16 waves), 1 block/CU.
// 15 barrier-stages/module; sG gate buffer; sBias dbuf in LDS; hoisted addrs.
// ---------------------------------------------------------------------------
struct ChainArgs {
  const float* feat_in;
  const float* S;
  const unsigned short* wt;      // 80 slots x 16384 shorts
  const float* bias_pack;        // 5 x 2304 floats
  float* feat_out;
  float* energy;
};

#define MFMA_ __builtin_amdgcn_mfma_f32_16x16x32_bf16

// A-parity AP in {0,1}: +AP*4352 shorts; swb parity SP: +SP*16384 shorts.
#define G128(AP, SP, ACC) { \
  short8 a0_ = *(const short8*)(aB + (AP)*4352); \
  short8 a1_ = *(const short8*)(aB + (AP)*4352 + 32); \
  short8 a2_ = *(const short8*)(aB + (AP)*4352 + 64); \
  short8 a3_ = *(const short8*)(aB + (AP)*4352 + 96); \
  ACC = MFMA_(a0_, *(const short8*)(b0 + (SP)*16384), ACC, 0, 0, 0); \
  ACC = MFMA_(a1_, *(const short8*)(b1 + (SP)*16384), ACC, 0, 0, 0); \
  ACC = MFMA_(a2_, *(const short8*)(b2 + (SP)*16384), ACC, 0, 0, 0); \
  ACC = MFMA_(a3_, *(const short8*)(b3 + (SP)*16384), ACC, 0, 0, 0); }

#define WSSPM(AP, V) { \
  wB[(AP)*4352]       = f2bf(sspf((V)[0])); \
  wB[(AP)*4352 + 136] = f2bf(sspf((V)[1])); \
  wB[(AP)*4352 + 272] = f2bf(sspf((V)[2])); \
  wB[(AP)*4352 + 408] = f2bf(sspf((V)[3])); }

// One full module, swb start-parity S0 compile-time.
#define MODBODY(S0) { \
  const float* bl = &sB[(S0)][0]; \
  /* G1: gate(sG) + W_J  [reads A0, swb[S0]] */ \
  dma32k(wtp + 2*16384, swb[(S0)^1], w, lane); \
  gG = Z; \
  { short8 s0_ = *(const short8*)(aS); short8 s1_ = *(const short8*)(aS + 32); \
    gG = MFMA_(s0_, *(const short8*)(g0), gG, 0, 0, 0); \
    gG = MFMA_(s1_, *(const short8*)(g1), gG, 0, 0, 0); } \
  fm = Z; G128(0, (S0), fm); \
  { float bv = bl[col0]; \
    for (int r = 0; r < 4; ++r) fm[r] = sspf(fm[r] + bv); } \
  __syncthreads(); \
  /* G2: W_I -> proto -> A1 ; prefetch next gate */ \
  dma32k(wtp + 3*16384, swb[(S0)], w, lane); \
  if (l < 4) dma16k(wtp + 16*16384, sG, w, lane); \
  t4 = Z; G128(0, (S0)^1, t4); \
  { float bv = bl[128 + col0]; \
    for (int r = 0; r < 4; ++r) xf[r] = fm[r]*gG[r] + sspf(t4[r] + bv); } \
  WSSPM(1, xf); \
  __syncthreads(); \
  /* G3..G8: ri x3 */ \
  dma32k(wtp + 4*16384, swb[(S0)^1], w, lane); \
  t4 = Z; G128(1, (S0), t4); \
  { float bv = bl[2*128 + col0]; for (int r = 0; r < 4; ++r) t4[r] += bv; } \
  WSSPM(0, t4); __syncthreads(); \
  dma32k(wtp + 5*16384, swb[(S0)], w, lane); \
  t4 = Z; G128(0, (S0)^1, t4); \
  { float bv = bl[3*128 + col0]; for (int r = 0; r < 4; ++r) xf[r] += t4[r] + bv; } \
  WSSPM(1, xf); __syncthreads(); \
  dma32k(wtp + 6*16384, swb[(S0)^1], w, lane); \
  t4 = Z; G128(1, (S0), t4); \
  { float bv = bl[4*128 + col0]; for (int r = 0; r < 4; ++r) t4[r] += bv; } \
  WSSPM(0, t4); __syncthreads(); \
  dma32k(wtp + 7*16384, swb[(S0)], w, lane); \
  t4 = Z; G128(0, (S0)^1, t4); \
  { float bv = bl[5*128 + col0]; for (int r = 0; r < 4; ++r) xf[r] += t4[r] + bv; } \
  WSSPM(1, xf); __syncthreads(); \
  dma32k(wtp + 8*16384, swb[(S0)^1], w, lane); \
  t4 = Z; G128(1, (S0), t4); \
  { float bv = bl[6*128 + col0]; for (int r = 0; r < 4; ++r) t4[r] += bv; } \
  WSSPM(0, t4); __syncthreads(); \
  dma32k(wtp + 9*16384, swb[(S0)], w, lane); \
  t4 = Z; G128(0, (S0)^1, t4); \
  { float bv = bl[7*128 + col0]; for (int r = 0; r < 4; ++r) xf[r] += t4[r] + bv; } \
  WSSPM(1, xf); __syncthreads(); \
  /* G9: W_int */ \
  dma32k(wtp + 10*16384, swb[(S0)^1], w, lane); \
  t4 = Z; G128(1, (S0), t4); \
  { float bv = bl[8*128 + col0]; float gv = bl[15*128 + col0]; \
    for (int r = 0; r < 4; ++r) xf[r] = ff[r]*gv + t4[r] + bv; } \
  WSSPM(0, xf); __syncthreads(); \
  /* G10..G13: ra x2 */ \
  dma32k(wtp + 11*16384, swb[(S0)], w, lane); \
  t4 = Z; G128(0, (S0)^1, t4); \
  { float bv = bl[9*128 + col0]; for (int r = 0; r < 4; ++r) t4[r] += bv; } \
  WSSPM(1, t4); __syncthreads(); \
  dma32k(wtp + 12*16384, swb[(S0)^1], w, lane); \
  t4 = Z; G128(1, (S0), t4); \
  { float bv = bl[10*128 + col0]; for (int r = 0; r < 4; ++r) xf[r] += t4[r] + bv; } \
  WSSPM(0, xf); __syncthreads(); \
  dma32k(wtp + 13*16384, swb[(S0)], w, lane); \
  t4 = Z; G128(0, (S0)^1, t4); \
  { float bv = bl[11*128 + col0]; for (int r = 0; r < 4; ++r) t4[r] += bv; } \
  WSSPM(1, t4); __syncthreads(); \
  dma32k(wtp + 14*16384, swb[(S0)^1], w, lane); \
  if (l < 4 && w < 9) \
    dma16((const char*)A.bias_pack + (size_t)(l + 1) * 9216 + w * 1024 + lane * 16, \
          (char*)&sB[(S0)^1][0] + w * 1024); \
  t4 = Z; G128(1, (S0), t4); \
  { float bv = bl[12*128 + col0]; for (int r = 0; r < 4; ++r) xf[r] += t4[r] + bv; } \
  WSSPM(0, xf); __syncthreads(); \
  ff = xf; \
  if (l == 4) { \
    for (int r = 0; r < 4; ++r) \
      A.feat_out[(size_t)(row0 + arow + quad*4 + r) * 128 + col0] = xf[r]; \
  } \
  /* G14: ro1 */ \
  dma32k(wtp + 15*16384, swb[(S0)], w, lane); \
  t4 = Z; G128(0, (S0)^1, t4); \
  { float bv = bl[13*128 + col0]; for (int r = 0; r < 4; ++r) t4[r] += bv; } \
  WSSPM(1, t4); __syncthreads(); \
  /* G15: ro2 + energy */ \
  if (l < 4) dma32k(wtp + 17*16384, swb[(S0)^1], w, lane); \
  t4 = Z; G128(1, (S0), t4); \
  { float bv = bl[14*128 + col0]; float wv = bl[16*128 + col0]; \
    p0 += sspf(xf[0] + t4[0] + bv) * wv; \
    p1 += sspf(xf[1] + t4[1] + bv) * wv; \
    p2 += sspf(xf[2] + t4[2] + bv) * wv; \
    p3 += sspf(xf[3] + t4[3] + bv) * wv; } \
  bsum += bl[17*128]; \
  __syncthreads(); }

__global__ __launch_bounds__(1024, 4) void chain_kernel(ChainArgs A) {
  __shared__ __align__(16) unsigned short swb[2][16384];   // 64 KB weight dbuf
  __shared__ __align__(16) unsigned short sG[8192];        // 16 KB gate
  __shared__ __align__(16) unsigned short sA[2][32 * 136]; // 17.4 KB
  __shared__ __align__(16) unsigned short sS[32 * 72];     // 4.5 KB
  __shared__ __align__(16) float sB[2][2304];              // 18.4 KB bias dbuf
  __shared__ float sE[32];

  const int tid  = threadIdx.x;
  const int row0 = blockIdx.x * 32;
  const int lane = tid & 63;
  const int w    = tid >> 6;       // 0..15
  const int g    = w >> 3;         // row group 0..1
  const int c    = w & 7;          // col 16-chunk 0..7
  const int l16  = lane & 15;
  const int quad = lane >> 4;
  const int arow = 16 * g;
  const int col0 = 16 * c + l16;
  const int l8   = l16 & 7;

  // hoisted thread-invariant LDS addresses (stage parity applied via imm offs)
  const unsigned short* aB = &sA[0][0] + (arow + l16) * 136 + quad * 8;
  unsigned short*       wB = &sA[0][0] + (arow + quad * 4) * 136 + col0;
  const unsigned short* b0 = &swb[0][0] + col0 * 128 + (((quad + 0) ^ l16) * 8);
  const unsigned short* b1 = &swb[0][0] + col0 * 128 + (((quad + 4) ^ l16) * 8);
  const unsigned short* b2 = &swb[0][0] + col0 * 128 + (((quad + 8) ^ l16) * 8);
  const unsigned short* b3 = &swb[0][0] + col0 * 128 + (((quad + 12) ^ l16) * 8);
  const unsigned short* aS = &sS[0] + (arow + l16) * 72 + quad * 8;
  const unsigned short* g0 = &sG[0] + col0 * 64 + (((quad + 0) ^ l8) * 8);
  const unsigned short* g1 = &sG[0] + col0 * 64 + (((quad + 4) ^ l8) * 8);

  // prologue DMAs: module-0 gate, W_J, biases
  dma16k(A.wt, sG, w, lane);
  dma32k(A.wt + 16384, swb[0], w, lane);
  if (w < 9)
    dma16((const char*)A.bias_pack + w * 1024 + lane * 16, (char*)&sB[0][0] + w * 1024);

  for (int i = tid; i < 32 * 64; i += 1024) {
    int r = i >> 6, k = i & 63;
    sS[r * 72 + k] = f2bf(A.S[(size_t)(row0 + r) * 64 + k]);
  }
  for (int i = tid; i < 32 * 128; i += 1024) {
    int r = i >> 7, k = i & 127;
    sA[0][r * 136 + k] = f2bf(sspf(A.feat_in[(size_t)(row0 + r) * 128 + k]));
  }
  float4v ff;
#pragma unroll
  for (int r = 0; r < 4; ++r)
    ff[r] = A.feat_in[(size_t)(row0 + arow + quad * 4 + r) * 128 + col0];
  if (tid < 32) sE[tid] = 0.0f;
  __syncthreads();

  const float4v Z = {0.f, 0.f, 0.f, 0.f};
  float4v gG, fm, xf, t4;
  float p0 = 0.f, p1 = 0.f, p2 = 0.f, p3 = 0.f, bsum = 0.f;

#pragma unroll 1
  for (int l = 0; l < 5; ++l) {
    const unsigned short* wtp = A.wt + (size_t)l * 16 * 16384;
    if ((l & 1) == 0) MODBODY(0) else MODBODY(1)
  }

  // ---- energy reduction (within 16-lane groups, then across 8 c-waves)
#pragma unroll
  for (int o = 1; o < 16; o <<= 1) {
    p0 += __shfl_xor(p0, o, 64);
    p1 += __shfl_xor(p1, o, 64);
    p2 += __shfl_xor(p2, o, 64);
    p3 += __shfl_xor(p3, o, 64);
  }
  if (l16 == 0) {
    atomicAdd(&sE[arow + quad * 4 + 0], p0);
    atomicAdd(&sE[arow + quad * 4 + 1], p1);
    atomicAdd(&sE[arow + quad * 4 + 2], p2);
    atomicAdd(&sE[arow + quad * 4 + 3], p3);
  }
  __syncthreads();
  if (tid < 32) A.energy[row0 + tid] = sE[tid] + bsum;
}

// ---------------------------------------------------------------------------
extern "C" void kernel_launch(void* const* d_in, const int* in_sizes, int n_in,
                              void* d_out, int out_size, void* d_ws, size_t ws_size,
                              hipStream_t stream) {
  const float* features = (const float*)d_in[1];
  const float* radial   = (const float*)d_in[2];
  const int*   idx12    = (const int*)  d_in[3];
  const float* W_I    = (const float*)d_in[4];
  const float* b_I    = (const float*)d_in[5];
  const float* W_J    = (const float*)d_in[6];
  const float* b_J    = (const float*)d_in[7];
  const float* W_gate = (const float*)d_in[8];
  const float* gvec   = (const float*)d_in[9];
  const float* W_int  = (const float*)d_in[10];
  const float* b_int  = (const float*)d_in[11];
  const float* ri_W1  = (const float*)d_in[12];
  const float* ri_b1  = (const float*)d_in[13];
  const float* ri_W2  = (const float*)d_in[14];
  const float* ri_b2  = (const float*)d_in[15];
  const float* ra_W1  = (const float*)d_in[16];
  const float* ra_b1  = (const float*)d_in[17];
  const float* ra_W2  = (const float*)d_in[18];
  const float* ra_b2  = (const float*)d_in[19];
  const float* ro_W1  = (const float*)d_in[20];
  const float* ro_b1  = (const float*)d_in[21];
  const float* ro_W2  = (const float*)d_in[22];
  const float* ro_b2  = (const float*)d_in[23];
  const float* W_out  = (const float*)d_in[24];
  const float* b_out  = (const float*)d_in[25];

  const int N = in_sizes[1] / 128;   // 8192
  const int P = in_sizes[3] / 2;     // 400000
  const int L = in_sizes[25];        // 5
  const int n2p = 2 * P;
  const int C = (n2p + NB - 1) / NB;

  // ws layout: S | bias_pack | Wt | H | tot | off | pairid
  float* S = (float*)d_ws;
  float* bias_pack = S + (size_t)N * 64;
  unsigned short* Wt = (unsigned short*)(bias_pack + 5 * 2304);
  unsigned int* H      = (unsigned int*)(Wt + (size_t)80 * 16384);
  unsigned int* tot    = H + (size_t)NB * 8192;
  unsigned int* off    = tot + N;
  unsigned int* pairid = off + N + 4;

  // ---- K1: fused weight prep + bias pack + hist
  K1Args k1;
  for (int l = 0; l < L; ++l) {
    const float* fx[16] = {
      W_gate + l * 8192,
      W_J + l * 16384, W_I + l * 16384,
      ri_W1 + (l * 3 + 0) * 16384, ri_W2 + (l * 3 + 0) * 16384,
      ri_W1 + (l * 3 + 1) * 16384, ri_W2 + (l * 3 + 1) * 16384,
      ri_W1 + (l * 3 + 2) * 16384, ri_W2 + (l * 3 + 2) * 16384,
      W_int + l * 16384,
      ra_W1 + (l * 2 + 0) * 16384, ra_W2 + (l * 2 + 0) * 16384,
      ra_W1 + (l * 2 + 1) * 16384, ra_W2 + (l * 2 + 1) * 16384,
      ro_W1 + l * 16384, ro_W2 + l * 16384 };
    for (int t = 0; t < 16; ++t) { k1.wsrc[l * 16 + t] = fx[t]; k1.isgate[l * 16 + t] = (t == 0); }
  }
  const float* bp[17] = { b_J, b_I,
    ri_b1, ri_b2, ri_b1 + 128, ri_b2 + 128, ri_b1 + 256, ri_b2 + 256,
    b_int, ra_b1, ra_b2, ra_b1 + 128, ra_b2 + 128, ro_b1, ro_b2, gvec, W_out };
  int st[17] = {128,128, 384,384,384,384,384,384, 128, 256,256,256,256, 128,128,128,128};
  for (int q = 0; q < 17; ++q) { k1.bp[q] = bp[q]; k1.bstride[q] = st[q]; }
  k1.b_out = b_out;
  k1.idx = idx12; k1.Wt = Wt; k1.bias_pack = bias_pack; k1.H = H;
  k1.n2p = n2p; k1.C = C;
  k1_prep<<<80 + 5 + NB, 256, 0, stream>>>(k1);

  // ---- S via LDS-hist sort + gather (no global atomics)
  col_scan<<<32, 256, 0, stream>>>(H, tot);
  place_pass<<<NB, 256, 0, stream>>>(idx12, H, tot, off, pairid, P, C);
  gather_kernel<<<N, 256, 0, stream>>>(radial, off, pairid, S);

  // ---- fused 5-module chain
  ChainArgs ca;
  ca.feat_in   = features;
  ca.S         = S;
  ca.wt        = Wt;
  ca.bias_pack = bias_pack;
  ca.energy    = (float*)d_out;
  ca.feat_out  = (float*)d_out + N;
  chain_kernel<<<N / 32, 1024, 0, stream>>>(ca);
}